// Round 2
// baseline (194.987 us; speedup 1.0000x reference)
//
#include <hip/hip_runtime.h>
#include <hip/hip_bf16.h>
#include <math.h>

// Weighted-MAE loss: total = sum(w[bin(y)] * |p - y|), count = #valid, out = total/count.
// bin = searchsorted(edge, y, 'right') - 1; valid iff 0 <= bin < n_bins.
//
// R6 post-mortem: `nt` on the streaming loads cost +77% dur at IDENTICAL
// FETCH_SIZE and proportionally lower VALUBusy -> pure latency increase at
// fixed in-flight capacity (confirms the latency x MSHR-capacity model; nt
// bypasses the near tier it was hitting, saves nothing). REVERTED.
// R7: isolate the second R6 change (fused last-block finish, kept). Ticket is
// one ACQ_REL agent-scope atomic per block (release: psum stores visible
// across XCDs; acquire on the winner: same atomic's ordering).

#define MAXB 8
#define NB   1024       // 4096 waves; n=16.7M -> exactly 4 chunks of 1024 floats/wave
#define BLOCK 256

typedef float vf4 __attribute__((ext_vector_type(4)));

__device__ __forceinline__ float to_sgpr(float x) {
    return __uint_as_float(__builtin_amdgcn_readfirstlane(__float_as_uint(x)));
}

#define ISSUE(Y0,Y1,Y2,Y3,P0,P1,P2,P3, YB, PB)                                      \
    asm volatile("global_load_dwordx4 %0, %1, off"             : "=v"(Y0) : "v"(YB)); \
    asm volatile("global_load_dwordx4 %0, %1, off offset:1024" : "=v"(Y1) : "v"(YB)); \
    asm volatile("global_load_dwordx4 %0, %1, off offset:2048" : "=v"(Y2) : "v"(YB)); \
    asm volatile("global_load_dwordx4 %0, %1, off offset:3072" : "=v"(Y3) : "v"(YB)); \
    asm volatile("global_load_dwordx4 %0, %1, off"             : "=v"(P0) : "v"(PB)); \
    asm volatile("global_load_dwordx4 %0, %1, off offset:1024" : "=v"(P1) : "v"(PB)); \
    asm volatile("global_load_dwordx4 %0, %1, off offset:2048" : "=v"(P2) : "v"(PB)); \
    asm volatile("global_load_dwordx4 %0, %1, off offset:3072" : "=v"(P3) : "v"(PB));

// data-tied waitcnt (R4 lesson): consumers cannot be hoisted above it
#define WAITN(N, Y0,Y1,Y2,Y3,P0,P1,P2,P3)                                           \
    asm volatile("s_waitcnt vmcnt(" #N ")"                                          \
        : "+v"(Y0), "+v"(Y1), "+v"(Y2), "+v"(Y3),                                   \
          "+v"(P0), "+v"(P1), "+v"(P2), "+v"(P3) :: "memory");

#define COMPUTE(F, Y0,Y1,Y2,Y3,P0,P1,P2,P3)                                         \
    F(Y0.x,P0.x); F(Y0.y,P0.y); F(Y0.z,P0.z); F(Y0.w,P0.w);                         \
    F(Y1.x,P1.x); F(Y1.y,P1.y); F(Y1.z,P1.z); F(Y1.w,P1.w);                         \
    F(Y2.x,P2.x); F(Y2.y,P2.y); F(Y2.z,P2.z); F(Y2.w,P2.w);                         \
    F(Y3.x,P3.x); F(Y3.y,P3.y); F(Y3.z,P3.z); F(Y3.w,P3.w);

// software-pipelined chunk walk; PROC is a lambda(yy, pp)
template <typename F>
__device__ __forceinline__ void pipeline(const float* y, const float* p,
                                         int nchunk, int wid, int nwaves, int lane,
                                         F&& proc)
{
    int c = wid;
    if (c >= nchunk) return;
    vf4 ya0, ya1, ya2, ya3, pa0, pa1, pa2, pa3;
    vf4 yb0, yb1, yb2, yb3, pb0, pb1, pb2, pb3;
    {
        const float* yb_ = y + ((size_t)c << 10) + lane * 4;
        const float* pb_ = p + ((size_t)c << 10) + lane * 4;
        ISSUE(ya0,ya1,ya2,ya3,pa0,pa1,pa2,pa3, yb_, pb_)
    }
    for (;;) {
        int c2 = c + nwaves;
        bool more = (c2 < nchunk);
        if (more) {
            const float* yb_ = y + ((size_t)c2 << 10) + lane * 4;
            const float* pb_ = p + ((size_t)c2 << 10) + lane * 4;
            ISSUE(yb0,yb1,yb2,yb3,pb0,pb1,pb2,pb3, yb_, pb_)
            WAITN(8, ya0,ya1,ya2,ya3,pa0,pa1,pa2,pa3)
        } else {
            WAITN(0, ya0,ya1,ya2,ya3,pa0,pa1,pa2,pa3)
        }
        COMPUTE(proc, ya0,ya1,ya2,ya3,pa0,pa1,pa2,pa3)
        if (!more) break;

        int c3 = c2 + nwaves;
        bool more2 = (c3 < nchunk);
        if (more2) {
            const float* yb_ = y + ((size_t)c3 << 10) + lane * 4;
            const float* pb_ = p + ((size_t)c3 << 10) + lane * 4;
            ISSUE(ya0,ya1,ya2,ya3,pa0,pa1,pa2,pa3, yb_, pb_)
            WAITN(8, yb0,yb1,yb2,yb3,pb0,pb1,pb2,pb3)
        } else {
            WAITN(0, yb0,yb1,yb2,yb3,pb0,pb1,pb2,pb3)
        }
        COMPUTE(proc, yb0,yb1,yb2,yb3,pb0,pb1,pb2,pb3)
        if (!more2) break;
        c = c3;
    }
}

__global__ __launch_bounds__(BLOCK) void wmae_partial(
    const float* __restrict__ y, const float* __restrict__ p,
    const float* __restrict__ weights, const float* __restrict__ edge,
    int n, int n_bins, int n_edges,
    float* __restrict__ psum, float* __restrict__ pcnt,
    unsigned* __restrict__ done, float* __restrict__ out)
{
    float sum = 0.0f;
    int   cnt = 0;

    const int lane   = threadIdx.x & 63;
    const int wid    = blockIdx.x * (BLOCK / 64) + (threadIdx.x >> 6);
    const int nwaves = gridDim.x * (BLOCK / 64);
    const int tid    = blockIdx.x * BLOCK + threadIdx.x;

    // ---- detect the canonical radar-QPE table (wave-uniform, once) ----
    bool fast = (n_bins == 7) && (n_edges == 8);
    if (fast) {
        const float ce[8] = {0.0f, 0.1f, 10.0f, 20.0f, 30.0f, 40.0f, 50.0f, 100.0f};
        const float cw[7] = {0.1f, 1.0f, 2.0f, 4.0f, 8.0f, 16.0f, 32.0f};
        for (int j = 0; j < 8; ++j) fast = fast && (edge[j] == ce[j]);
        for (int j = 0; j < 7; ++j) fast = fast && (weights[j] == cw[j]);
    }

    if (fast) {
        // w(y) for y in [10,50): 2^floor(y/10); [0.1,10): 1 = 2^0; [50,100): 32 = 2^5;
        // [0,0.1): 0.1 ; outside [0,100): 0. count = #(w != 0) (weights verified nonzero).
        auto proc = [&](float yy, float pp) {
            float t = yy * 0.1f;
            int   i = (int)t;              // trunc; negative y handled by guard below
            i = min(i, 5);
            float w = ldexpf(1.0f, i);     // v_ldexp_f32
            w = (yy < 0.1f)   ? 0.1f : w;
            w = (yy < 0.0f)   ? 0.0f : w;
            w = (yy >= 100.f) ? 0.0f : w;
            sum += w * fabsf(pp - yy);
            cnt += (w != 0.0f) ? 1 : 0;
        };
        const int nchunk = n >> 10;
        pipeline(y, p, nchunk, wid, nwaves, lane, proc);
        const int n1 = nchunk << 10;
        for (int k = n1 + tid; k < n; k += gridDim.x * BLOCK) proc(y[k], p[k]);
    } else if (n_bins <= MAXB) {
        // SGPR compare/select chain (general small-table path)
        float ev[MAXB], wv[MAXB];
#pragma unroll
        for (int j = 0; j < MAXB; ++j) {
            ev[j] = to_sgpr((j < n_bins && j < n_edges) ? edge[j] : 3.4e38f);
            wv[j] = to_sgpr((j < n_bins) ? weights[j] : 0.0f);
        }
        const float e0  = to_sgpr(edge[0]);
        const float eup = to_sgpr((n_bins < n_edges) ? edge[n_bins] : 3.4e38f);
        auto proc = [&](float yy, float pp) {
            float w = 0.0f;
#pragma unroll
            for (int j = 0; j < MAXB; ++j) w = (yy >= ev[j]) ? wv[j] : w;
            bool valid = (yy >= e0) && (yy < eup);
            sum += (valid ? w : 0.0f) * fabsf(pp - yy);
            cnt += valid ? 1 : 0;
        };
        const int nchunk = n >> 10;
        pipeline(y, p, nchunk, wid, nwaves, lane, proc);
        const int n1 = nchunk << 10;
        for (int k = n1 + tid; k < n; k += gridDim.x * BLOCK) proc(y[k], p[k]);
    } else {
        // fully generic scalar path
        for (int k = tid; k < n; k += gridDim.x * BLOCK) {
            float yy = y[k], pp = p[k];
            float w = 0.0f;
            for (int j = 0; j < n_bins; ++j) w = (yy >= edge[j]) ? weights[j] : w;
            bool valid = (yy >= edge[0]) && (n_bins < n_edges ? (yy < edge[n_bins]) : true);
            sum += (valid ? w : 0.0f) * fabsf(pp - yy);
            cnt += valid ? 1 : 0;
        }
    }

    // wave (64-lane) reduce
#pragma unroll
    for (int off = 32; off > 0; off >>= 1) {
        sum += __shfl_down(sum, off, 64);
        cnt += __shfl_down(cnt, off, 64);
    }
    __shared__ float wsum[BLOCK / 64];
    __shared__ int   wcnt[BLOCK / 64];
    __shared__ unsigned lastflag;
    const int wave = threadIdx.x >> 6;
    if (lane == 0) { wsum[wave] = sum; wcnt[wave] = cnt; }
    __syncthreads();
    if (threadIdx.x == 0) {
        float s = 0.0f; int c = 0;
#pragma unroll
        for (int w2 = 0; w2 < BLOCK / 64; ++w2) { s += wsum[w2]; c += wcnt[w2]; }
        psum[blockIdx.x] = s;
        pcnt[blockIdx.x] = (float)c;   // counts are integers < 2^24: exact in fp32
        unsigned t = ~0u;
        if (done != nullptr) {
            // ACQ_REL agent-scope ticket: release makes psum/pcnt stores visible
            // device-wide; acquire (on the winner) synchronizes-with all prior
            // releases on `done` -> partials readable across XCDs.
            t = __hip_atomic_fetch_add(done, 1u, __ATOMIC_ACQ_REL,
                                       __HIP_MEMORY_SCOPE_AGENT);
        }
        lastflag = (t == (unsigned)gridDim.x - 1u) ? 1u : 0u;
    }
    __syncthreads();

    // ---- fused finish: the last-arriving block reduces the partials ----
    // Summation order is identical to the old wmae_final kernel => bitwise-same result.
    if (lastflag) {
        float S = 0.0f, C = 0.0f;
        for (int i = threadIdx.x; i < (int)gridDim.x; i += BLOCK) { S += psum[i]; C += pcnt[i]; }
#pragma unroll
        for (int off = 32; off > 0; off >>= 1) {
            S += __shfl_down(S, off, 64);
            C += __shfl_down(C, off, 64);
        }
        __shared__ float fsum[BLOCK / 64];
        __shared__ float fcnt[BLOCK / 64];
        if (lane == 0) { fsum[wave] = S; fcnt[wave] = C; }
        __syncthreads();
        if (threadIdx.x == 0) {
            float FS = 0.0f, FC = 0.0f;
#pragma unroll
            for (int w2 = 0; w2 < BLOCK / 64; ++w2) { FS += fsum[w2]; FC += fcnt[w2]; }
            out[0] = FS / FC;
        }
    }
}

// fallback path (only used if the workspace is too small for the ticket word)
__global__ __launch_bounds__(BLOCK) void wmae_final(
    const float* __restrict__ psum, const float* __restrict__ pcnt,
    int nparts, float* __restrict__ out)
{
    float s = 0.0f, c = 0.0f;
    for (int i = threadIdx.x; i < nparts; i += BLOCK) { s += psum[i]; c += pcnt[i]; }
#pragma unroll
    for (int off = 32; off > 0; off >>= 1) {
        s += __shfl_down(s, off, 64);
        c += __shfl_down(c, off, 64);
    }
    __shared__ float wsum[BLOCK / 64];
    __shared__ float wcnt[BLOCK / 64];
    const int wave = threadIdx.x >> 6;
    const int lane = threadIdx.x & 63;
    if (lane == 0) { wsum[wave] = s; wcnt[wave] = c; }
    __syncthreads();
    if (threadIdx.x == 0) {
        float S = 0.0f, C = 0.0f;
#pragma unroll
        for (int w2 = 0; w2 < BLOCK / 64; ++w2) { S += wsum[w2]; C += wcnt[w2]; }
        out[0] = S / C;
    }
}

extern "C" void kernel_launch(void* const* d_in, const int* in_sizes, int n_in,
                              void* d_out, int out_size, void* d_ws, size_t ws_size,
                              hipStream_t stream) {
    const float* y       = (const float*)d_in[0];
    const float* p       = (const float*)d_in[1];
    const float* weights = (const float*)d_in[2];
    const float* edge    = (const float*)d_in[3];
    const int n       = in_sizes[0];
    const int n_bins  = in_sizes[2];
    const int n_edges = in_sizes[3];

    float* psum   = (float*)d_ws;          // NB floats
    float* pcnt   = psum + NB;             // NB floats
    unsigned* done = (unsigned*)(pcnt + NB); // 1 uint ticket
    float* out    = (float*)d_out;

    const bool fused = ws_size >= (size_t)(2 * NB + 1) * sizeof(float);
    if (fused) {
        // graph-capturable memset node; resets the ticket before each replay
        hipMemsetAsync(done, 0, sizeof(unsigned), stream);
        wmae_partial<<<NB, BLOCK, 0, stream>>>(y, p, weights, edge,
                                               n, n_bins, n_edges, psum, pcnt, done, out);
    } else {
        wmae_partial<<<NB, BLOCK, 0, stream>>>(y, p, weights, edge,
                                               n, n_bins, n_edges, psum, pcnt, nullptr, out);
        wmae_final<<<1, BLOCK, 0, stream>>>(psum, pcnt, NB, out);
    }
}

// Round 3
// 148.974 us; speedup vs baseline: 1.3089x; 1.3089x over previous
//
#include <hip/hip_runtime.h>
#include <hip/hip_bf16.h>
#include <math.h>

// Weighted-MAE loss: total = sum(w[bin(y)] * |p - y|), count = #valid, out = total/count.
// bin = searchsorted(edge, y, 'right') - 1; valid iff 0 <= bin < n_bins.
//
// R7 post-mortem (final attribution):
//  - nt bit: NOT the R6 regression's main cause. FETCH identical, replays
//    tier-invariant; reverting it did not recover.
//  - Fused last-block ticket: THE regression. 1024 blocks finish near-
//    simultaneously -> 1024 same-address device-scope RMWs queue at the
//    coherence point; each block stalls on its own atomic before exit.
//    +33us (relaxed add + fence, R6) / +48us (ACQ_REL per-op, R7) tail.
//    Fusion trades a ~5us second dispatch for a ~50us contention tail: NET LOSS.
// => REVERTED to the harness-verified best structure (two kernels, no ticket):
//    42.5us partial @ 3.19 TB/s effective read = 101% of m13 copy read-side.
//    All levers tested: grid size, loads-in-flight, memory tier, VALU count,
//    nt, fusion -- invariant or negative. This is the streaming-read ceiling.

#define MAXB 8
#define NB   1024       // 4096 waves; n=16.7M -> exactly 4 chunks of 1024 floats/wave
#define BLOCK 256

typedef float vf4 __attribute__((ext_vector_type(4)));

__device__ __forceinline__ float to_sgpr(float x) {
    return __uint_as_float(__builtin_amdgcn_readfirstlane(__float_as_uint(x)));
}

#define ISSUE(Y0,Y1,Y2,Y3,P0,P1,P2,P3, YB, PB)                                      \
    asm volatile("global_load_dwordx4 %0, %1, off"             : "=v"(Y0) : "v"(YB)); \
    asm volatile("global_load_dwordx4 %0, %1, off offset:1024" : "=v"(Y1) : "v"(YB)); \
    asm volatile("global_load_dwordx4 %0, %1, off offset:2048" : "=v"(Y2) : "v"(YB)); \
    asm volatile("global_load_dwordx4 %0, %1, off offset:3072" : "=v"(Y3) : "v"(YB)); \
    asm volatile("global_load_dwordx4 %0, %1, off"             : "=v"(P0) : "v"(PB)); \
    asm volatile("global_load_dwordx4 %0, %1, off offset:1024" : "=v"(P1) : "v"(PB)); \
    asm volatile("global_load_dwordx4 %0, %1, off offset:2048" : "=v"(P2) : "v"(PB)); \
    asm volatile("global_load_dwordx4 %0, %1, off offset:3072" : "=v"(P3) : "v"(PB));

// data-tied waitcnt (R4 lesson): consumers cannot be hoisted above it
#define WAITN(N, Y0,Y1,Y2,Y3,P0,P1,P2,P3)                                           \
    asm volatile("s_waitcnt vmcnt(" #N ")"                                          \
        : "+v"(Y0), "+v"(Y1), "+v"(Y2), "+v"(Y3),                                   \
          "+v"(P0), "+v"(P1), "+v"(P2), "+v"(P3) :: "memory");

#define COMPUTE(F, Y0,Y1,Y2,Y3,P0,P1,P2,P3)                                         \
    F(Y0.x,P0.x); F(Y0.y,P0.y); F(Y0.z,P0.z); F(Y0.w,P0.w);                         \
    F(Y1.x,P1.x); F(Y1.y,P1.y); F(Y1.z,P1.z); F(Y1.w,P1.w);                         \
    F(Y2.x,P2.x); F(Y2.y,P2.y); F(Y2.z,P2.z); F(Y2.w,P2.w);                         \
    F(Y3.x,P3.x); F(Y3.y,P3.y); F(Y3.z,P3.z); F(Y3.w,P3.w);

// software-pipelined chunk walk; PROC is a lambda(yy, pp)
template <typename F>
__device__ __forceinline__ void pipeline(const float* y, const float* p,
                                         int nchunk, int wid, int nwaves, int lane,
                                         F&& proc)
{
    int c = wid;
    if (c >= nchunk) return;
    vf4 ya0, ya1, ya2, ya3, pa0, pa1, pa2, pa3;
    vf4 yb0, yb1, yb2, yb3, pb0, pb1, pb2, pb3;
    {
        const float* yb_ = y + ((size_t)c << 10) + lane * 4;
        const float* pb_ = p + ((size_t)c << 10) + lane * 4;
        ISSUE(ya0,ya1,ya2,ya3,pa0,pa1,pa2,pa3, yb_, pb_)
    }
    for (;;) {
        int c2 = c + nwaves;
        bool more = (c2 < nchunk);
        if (more) {
            const float* yb_ = y + ((size_t)c2 << 10) + lane * 4;
            const float* pb_ = p + ((size_t)c2 << 10) + lane * 4;
            ISSUE(yb0,yb1,yb2,yb3,pb0,pb1,pb2,pb3, yb_, pb_)
            WAITN(8, ya0,ya1,ya2,ya3,pa0,pa1,pa2,pa3)
        } else {
            WAITN(0, ya0,ya1,ya2,ya3,pa0,pa1,pa2,pa3)
        }
        COMPUTE(proc, ya0,ya1,ya2,ya3,pa0,pa1,pa2,pa3)
        if (!more) break;

        int c3 = c2 + nwaves;
        bool more2 = (c3 < nchunk);
        if (more2) {
            const float* yb_ = y + ((size_t)c3 << 10) + lane * 4;
            const float* pb_ = p + ((size_t)c3 << 10) + lane * 4;
            ISSUE(ya0,ya1,ya2,ya3,pa0,pa1,pa2,pa3, yb_, pb_)
            WAITN(8, yb0,yb1,yb2,yb3,pb0,pb1,pb2,pb3)
        } else {
            WAITN(0, yb0,yb1,yb2,yb3,pb0,pb1,pb2,pb3)
        }
        COMPUTE(proc, yb0,yb1,yb2,yb3,pb0,pb1,pb2,pb3)
        if (!more2) break;
        c = c3;
    }
}

__global__ __launch_bounds__(BLOCK) void wmae_partial(
    const float* __restrict__ y, const float* __restrict__ p,
    const float* __restrict__ weights, const float* __restrict__ edge,
    int n, int n_bins, int n_edges,
    float* __restrict__ psum, float* __restrict__ pcnt)
{
    float sum = 0.0f;
    int   cnt = 0;

    const int lane   = threadIdx.x & 63;
    const int wid    = blockIdx.x * (BLOCK / 64) + (threadIdx.x >> 6);
    const int nwaves = gridDim.x * (BLOCK / 64);
    const int tid    = blockIdx.x * BLOCK + threadIdx.x;

    // ---- detect the canonical radar-QPE table (wave-uniform, once) ----
    bool fast = (n_bins == 7) && (n_edges == 8);
    if (fast) {
        const float ce[8] = {0.0f, 0.1f, 10.0f, 20.0f, 30.0f, 40.0f, 50.0f, 100.0f};
        const float cw[7] = {0.1f, 1.0f, 2.0f, 4.0f, 8.0f, 16.0f, 32.0f};
        for (int j = 0; j < 8; ++j) fast = fast && (edge[j] == ce[j]);
        for (int j = 0; j < 7; ++j) fast = fast && (weights[j] == cw[j]);
    }

    if (fast) {
        // w(y) for y in [10,50): 2^floor(y/10); [0.1,10): 1 = 2^0; [50,100): 32 = 2^5;
        // [0,0.1): 0.1 ; outside [0,100): 0. count = #(w != 0) (weights verified nonzero).
        auto proc = [&](float yy, float pp) {
            float t = yy * 0.1f;
            int   i = (int)t;              // trunc; negative y handled by guard below
            i = min(i, 5);
            float w = ldexpf(1.0f, i);     // v_ldexp_f32
            w = (yy < 0.1f)   ? 0.1f : w;
            w = (yy < 0.0f)   ? 0.0f : w;
            w = (yy >= 100.f) ? 0.0f : w;
            sum += w * fabsf(pp - yy);
            cnt += (w != 0.0f) ? 1 : 0;
        };
        const int nchunk = n >> 10;
        pipeline(y, p, nchunk, wid, nwaves, lane, proc);
        const int n1 = nchunk << 10;
        for (int k = n1 + tid; k < n; k += gridDim.x * BLOCK) proc(y[k], p[k]);
    } else if (n_bins <= MAXB) {
        // SGPR compare/select chain (general small-table path)
        float ev[MAXB], wv[MAXB];
#pragma unroll
        for (int j = 0; j < MAXB; ++j) {
            ev[j] = to_sgpr((j < n_bins && j < n_edges) ? edge[j] : 3.4e38f);
            wv[j] = to_sgpr((j < n_bins) ? weights[j] : 0.0f);
        }
        const float e0  = to_sgpr(edge[0]);
        const float eup = to_sgpr((n_bins < n_edges) ? edge[n_bins] : 3.4e38f);
        auto proc = [&](float yy, float pp) {
            float w = 0.0f;
#pragma unroll
            for (int j = 0; j < MAXB; ++j) w = (yy >= ev[j]) ? wv[j] : w;
            bool valid = (yy >= e0) && (yy < eup);
            sum += (valid ? w : 0.0f) * fabsf(pp - yy);
            cnt += valid ? 1 : 0;
        };
        const int nchunk = n >> 10;
        pipeline(y, p, nchunk, wid, nwaves, lane, proc);
        const int n1 = nchunk << 10;
        for (int k = n1 + tid; k < n; k += gridDim.x * BLOCK) proc(y[k], p[k]);
    } else {
        // fully generic scalar path
        for (int k = tid; k < n; k += gridDim.x * BLOCK) {
            float yy = y[k], pp = p[k];
            float w = 0.0f;
            for (int j = 0; j < n_bins; ++j) w = (yy >= edge[j]) ? weights[j] : w;
            bool valid = (yy >= edge[0]) && (n_bins < n_edges ? (yy < edge[n_bins]) : true);
            sum += (valid ? w : 0.0f) * fabsf(pp - yy);
            cnt += valid ? 1 : 0;
        }
    }

    // wave (64-lane) reduce
#pragma unroll
    for (int off = 32; off > 0; off >>= 1) {
        sum += __shfl_down(sum, off, 64);
        cnt += __shfl_down(cnt, off, 64);
    }
    __shared__ float wsum[BLOCK / 64];
    __shared__ int   wcnt[BLOCK / 64];
    const int wave = threadIdx.x >> 6;
    if (lane == 0) { wsum[wave] = sum; wcnt[wave] = cnt; }
    __syncthreads();
    if (threadIdx.x == 0) {
        float s = 0.0f; int c = 0;
#pragma unroll
        for (int w2 = 0; w2 < BLOCK / 64; ++w2) { s += wsum[w2]; c += wcnt[w2]; }
        psum[blockIdx.x] = s;
        pcnt[blockIdx.x] = (float)c;   // counts are integers < 2^24: exact in fp32
    }
}

__global__ __launch_bounds__(BLOCK) void wmae_final(
    const float* __restrict__ psum, const float* __restrict__ pcnt,
    int nparts, float* __restrict__ out)
{
    float s = 0.0f, c = 0.0f;
    for (int i = threadIdx.x; i < nparts; i += BLOCK) { s += psum[i]; c += pcnt[i]; }
#pragma unroll
    for (int off = 32; off > 0; off >>= 1) {
        s += __shfl_down(s, off, 64);
        c += __shfl_down(c, off, 64);
    }
    __shared__ float wsum[BLOCK / 64];
    __shared__ float wcnt[BLOCK / 64];
    const int wave = threadIdx.x >> 6;
    const int lane = threadIdx.x & 63;
    if (lane == 0) { wsum[wave] = s; wcnt[wave] = c; }
    __syncthreads();
    if (threadIdx.x == 0) {
        float S = 0.0f, C = 0.0f;
#pragma unroll
        for (int w2 = 0; w2 < BLOCK / 64; ++w2) { S += wsum[w2]; C += wcnt[w2]; }
        out[0] = S / C;
    }
}

extern "C" void kernel_launch(void* const* d_in, const int* in_sizes, int n_in,
                              void* d_out, int out_size, void* d_ws, size_t ws_size,
                              hipStream_t stream) {
    const float* y       = (const float*)d_in[0];
    const float* p       = (const float*)d_in[1];
    const float* weights = (const float*)d_in[2];
    const float* edge    = (const float*)d_in[3];
    const int n       = in_sizes[0];
    const int n_bins  = in_sizes[2];
    const int n_edges = in_sizes[3];

    float* psum = (float*)d_ws;            // NB floats
    float* pcnt = psum + NB;               // NB floats
    float* out  = (float*)d_out;

    wmae_partial<<<NB, BLOCK, 0, stream>>>(y, p, weights, edge,
                                           n, n_bins, n_edges, psum, pcnt);
    wmae_final<<<1, BLOCK, 0, stream>>>(psum, pcnt, NB, out);
}